// Round 1
// baseline (164.034 us; speedup 1.0000x reference)
//
#include <hip/hip_runtime.h>
#include <math.h>

// spe_self_atten: out[b] = softmax( (Xb Xb^T) / max(n_i n_j, eps) ) Xb + Xb
// B=256, C=200 rows, L=1024. f32 in/out, bf16 MFMA internally.
// One workgroup per batch, 512 threads (8 waves). Residual folded via P += I.

typedef unsigned int uint32;
typedef __attribute__((ext_vector_type(8))) short bf16x8;   // 8 bf16 (4 VGPRs)
typedef __attribute__((ext_vector_type(4))) float f32x4;    // MFMA accum
typedef __attribute__((ext_vector_type(4))) uint32 u32x4;

#define CC 200
#define LL 1024
#define EPSV 1e-8f

__device__ __forceinline__ uint32 bfb(float f) {
  // f32 -> bf16 bits, round-to-nearest-even
  uint32 u = __float_as_uint(f);
  u += 0x7fffu + ((u >> 16) & 1u);
  return u >> 16;
}

__global__ __launch_bounds__(512, 2)
void spe_attn_kernel(const float* __restrict__ x, float* __restrict__ out) {
  const int tid  = threadIdx.x;
  const int lane = tid & 63;
  const int w    = tid >> 6;       // wave 0..7
  const int lm   = lane & 15;      // column lane within 16-group
  const int lg   = lane >> 4;      // k/row group 0..3
  const int bidx = blockIdx.x;
  const float* xb = x + (size_t)bidx * (CC * LL);
  float* ob       = out + (size_t)bidx * (CC * LL);

  // LDS layout (dwords), total 39120 dw = 156,480 B:
  //  pl   [0,24128)      : P bf16, 208 rows x 232 cols (116 dw row stride, ≡20 mod 32)
  //  xa0  [24128,31616)  : phase-1 slab buf A, 208 rows x 72 bf16 (36 dw, ≡4 mod 32)
  //  xa1  [31616,39104)  : phase-1 slab buf B
  //  xbuf [24128,38912)  : phase-2 chunk, 112 kpairs x 132 dw (aliases xa)
  //  norms [38912,39120) : 208 floats
  __shared__ uint32 LDS[39120];
  uint32* pl    = LDS;
  uint32* xa0   = LDS + 24128;
  uint32* xa1   = LDS + 31616;
  uint32* xbuf  = LDS + 24128;
  float*  norms = (float*)(LDS + 38912);

  const bool two = (w < 5);            // waves 0..4 own 2 row-blocks {w, w+8}
  const int rb0 = w;
  const int rb1 = two ? (w + 8) : w;

  // ---------------- Phase 1: Gram S = Xb Xb^T --------------------------------
  const f32x4 fz = {0.f, 0.f, 0.f, 0.f};
  f32x4 acc[2][13];
  #pragma unroll
  for (int i = 0; i < 2; ++i)
    #pragma unroll
    for (int j = 0; j < 13; ++j) acc[i][j] = fz;

  // zero pad rows 200..207 of both slab buffers (stay zero; staging writes rows<200)
  if (tid < 288) { xa0[7200 + tid] = 0u; xa1[7200 + tid] = 0u; }

  float4 vst[7];
  // stage slab 0 (k = 0..63): 200 rows x 16 float4
  #pragma unroll
  for (int i = 0; i < 7; ++i) {
    int idx = tid + i * 512;
    if (idx < 3200) {
      int row = idx >> 4, c4 = idx & 15;
      vst[i] = *(const float4*)(xb + row * LL + c4 * 4);
    }
  }
  #pragma unroll
  for (int i = 0; i < 7; ++i) {
    int idx = tid + i * 512;
    if (idx < 3200) {
      int row = idx >> 4, c4 = idx & 15;
      uint2 wv;
      wv.x = bfb(vst[i].x) | (bfb(vst[i].y) << 16);
      wv.y = bfb(vst[i].z) | (bfb(vst[i].w) << 16);
      *(uint2*)&xa0[row * 36 + c4 * 2] = wv;
    }
  }

  for (int s = 0; s < 16; ++s) {
    __syncthreads();   // slab s visible; prior reads of other buffer done
    if (s + 1 < 16) {  // issue next-slab global loads early (latency hides under MFMA)
      #pragma unroll
      for (int i = 0; i < 7; ++i) {
        int idx = tid + i * 512;
        if (idx < 3200) {
          int row = idx >> 4, c4 = idx & 15;
          vst[i] = *(const float4*)(xb + row * LL + (s + 1) * 64 + c4 * 4);
        }
      }
    }
    const uint32* cur = (s & 1) ? xa1 : xa0;
    #pragma unroll
    for (int ks = 0; ks < 2; ++ks) {
      bf16x8 a0 = *(const bf16x8*)&cur[(rb0 * 16 + lm) * 36 + ks * 16 + lg * 4];
      bf16x8 a1 = a0;
      if (two) a1 = *(const bf16x8*)&cur[(rb1 * 16 + lm) * 36 + ks * 16 + lg * 4];
      #pragma unroll
      for (int ct = 0; ct < 13; ++ct) {
        bf16x8 bf = *(const bf16x8*)&cur[(ct * 16 + lm) * 36 + ks * 16 + lg * 4];
        acc[0][ct] = __builtin_amdgcn_mfma_f32_16x16x32_bf16(a0, bf, acc[0][ct], 0, 0, 0);
        if (two)
          acc[1][ct] = __builtin_amdgcn_mfma_f32_16x16x32_bf16(a1, bf, acc[1][ct], 0, 0, 0);
      }
    }
    if (s + 1 < 16) {  // write staged regs -> other buffer
      uint32* nxt = (s & 1) ? xa0 : xa1;
      #pragma unroll
      for (int i = 0; i < 7; ++i) {
        int idx = tid + i * 512;
        if (idx < 3200) {
          int row = idx >> 4, c4 = idx & 15;
          uint2 wv;
          wv.x = bfb(vst[i].x) | (bfb(vst[i].y) << 16);
          wv.y = bfb(vst[i].z) | (bfb(vst[i].w) << 16);
          *(uint2*)&nxt[row * 36 + c4 * 2] = wv;
        }
      }
    }
  }

  // ---------------- norms from Gram diagonal ---------------------------------
  #pragma unroll
  for (int rbi = 0; rbi < 2; ++rbi) {
    if (rbi == 0 || two) {
      int rb = rbi ? rb1 : rb0;
      #pragma unroll
      for (int ct = 0; ct < 13; ++ct) {
        if (ct == rb) {   // static reg-array access, runtime guard
          #pragma unroll
          for (int r = 0; r < 4; ++r) {
            int ri = lg * 4 + r;
            if (lm == ri) norms[rb * 16 + ri] = sqrtf(acc[rbi][ct][r]);
          }
        }
      }
    }
  }
  __syncthreads();

  // ---------------- softmax rows + (P+I) -> LDS bf16 -------------------------
  float cn[13];
  #pragma unroll
  for (int ct = 0; ct < 13; ++ct) cn[ct] = norms[ct * 16 + lm];

  #pragma unroll
  for (int rbi = 0; rbi < 2; ++rbi) {
    if (rbi == 0 || two) {
      int rb = rbi ? rb1 : rb0;
      #pragma unroll
      for (int r = 0; r < 4; ++r) {
        int grow = rb * 16 + lg * 4 + r;
        float rn = norms[grow];
        float sv[13];
        float m = -INFINITY;
        #pragma unroll
        for (int ct = 0; ct < 13; ++ct) {
          int gc = ct * 16 + lm;
          float sval = acc[rbi][ct][r] / fmaxf(rn * cn[ct], EPSV);
          sval = (gc < CC) ? sval : -INFINITY;
          sv[ct] = sval;
          m = fmaxf(m, sval);
        }
        #pragma unroll
        for (int off = 1; off < 16; off <<= 1) m = fmaxf(m, __shfl_xor(m, off));
        float sum = 0.f;
        #pragma unroll
        for (int ct = 0; ct < 13; ++ct) {
          float e = __expf(sv[ct] - m);
          sv[ct] = e;
          sum += e;
        }
        #pragma unroll
        for (int off = 1; off < 16; off <<= 1) sum += __shfl_xor(sum, off);
        float inv = 1.0f / sum;
        #pragma unroll
        for (int ct = 0; ct < 13; ++ct) {
          int gc = ct * 16 + lm;
          float p = sv[ct] * inv + ((gc == grow) ? 1.0f : 0.0f);  // P += I (residual)
          uint32 pb = bfb(p);
          uint32 qb = (uint32)__shfl_xor((int)pb, 1);
          if (!(lane & 1)) pl[grow * 116 + ct * 8 + (lm >> 1)] = pb | (qb << 16);
        }
      }
      // zero P cols 200..231 for this row-block (K padding must be exactly 0)
      for (int i = lane; i < 256; i += 64)
        pl[(rb * 16 + (i >> 4)) * 116 + 100 + (i & 15)] = 0u;
    }
  }

  // ---------------- Phase 2: out = (P+I) @ Xb, 8 chunks of 128 cols ----------
  for (int nc = 0; nc < 8; ++nc) {
    const int n0 = nc * 128;
    __syncthreads();   // previous chunk fully consumed (and P visible on nc=0)
    // stage Xb[:, n0:n0+128] k-pair-interleaved: dword = bf16(x[2kp][n]) | bf16(x[2kp+1][n])<<16
    #pragma unroll
    for (int pass = 0; pass < 14; ++pass) {
      int kp = pass * 8 + w;       // wave-uniform
      int r0 = kp * 2, r1 = r0 + 1;
      int n = n0 + (lane << 1);
      float2 va = (r0 < CC) ? *(const float2*)(xb + r0 * LL + n) : make_float2(0.f, 0.f);
      float2 vb = (r1 < CC) ? *(const float2*)(xb + r1 * LL + n) : make_float2(0.f, 0.f);
      uint2 wv;
      wv.x = bfb(va.x) | (bfb(vb.x) << 16);
      wv.y = bfb(va.y) | (bfb(vb.y) << 16);
      *(uint2*)&xbuf[kp * 132 + (lane << 1)] = wv;
    }
    __syncthreads();

    f32x4 acc2[2][8];
    #pragma unroll
    for (int i = 0; i < 2; ++i)
      #pragma unroll
      for (int j = 0; j < 8; ++j) acc2[i][j] = fz;

    #pragma unroll
    for (int ks = 0; ks < 7; ++ks) {   // K = 224 (padded; P cols 200..223 are 0)
      bf16x8 a0 = *(const bf16x8*)&pl[(rb0 * 16 + lm) * 116 + ks * 16 + lg * 4];
      bf16x8 a1 = a0;
      if (two) a1 = *(const bf16x8*)&pl[(rb1 * 16 + lm) * 116 + ks * 16 + lg * 4];
      #pragma unroll
      for (int ct = 0; ct < 8; ++ct) {
        int kpb = ks * 16 + lg * 4;
        int col = ct * 16 + lm;
        u32x4 bv;
        bv[0] = xbuf[(kpb + 0) * 132 + col];
        bv[1] = xbuf[(kpb + 1) * 132 + col];
        bv[2] = xbuf[(kpb + 2) * 132 + col];
        bv[3] = xbuf[(kpb + 3) * 132 + col];
        bf16x8 bf = __builtin_bit_cast(bf16x8, bv);
        acc2[0][ct] = __builtin_amdgcn_mfma_f32_16x16x32_bf16(a0, bf, acc2[0][ct], 0, 0, 0);
        if (two)
          acc2[1][ct] = __builtin_amdgcn_mfma_f32_16x16x32_bf16(a1, bf, acc2[1][ct], 0, 0, 0);
      }
    }

    // store f32 outputs (rows < 200 only)
    #pragma unroll
    for (int rbi = 0; rbi < 2; ++rbi) {
      if (rbi == 0 || two) {
        int rb = rbi ? rb1 : rb0;
        #pragma unroll
        for (int ct = 0; ct < 8; ++ct) {
          #pragma unroll
          for (int r = 0; r < 4; ++r) {
            int grow = rb * 16 + lg * 4 + r;
            if (grow < CC) ob[grow * LL + n0 + ct * 16 + lm] = acc2[rbi][ct][r];
          }
        }
      }
    }
  }
}

extern "C" void kernel_launch(void* const* d_in, const int* in_sizes, int n_in,
                              void* d_out, int out_size, void* d_ws, size_t ws_size,
                              hipStream_t stream) {
  const float* x = (const float*)d_in[0];
  float* out = (float*)d_out;
  const int B = in_sizes[0] / (CC * LL);   // 256
  spe_attn_kernel<<<dim3(B), dim3(512), 0, stream>>>(x, out);
}